// Round 1
// baseline (427.663 us; speedup 1.0000x reference)
//
#include <hip/hip_runtime.h>
#include <stdint.h>

#define DEV_INLINE __device__ __forceinline__

typedef __bf16 bf16x8 __attribute__((ext_vector_type(8)));
typedef float f32x4 __attribute__((ext_vector_type(4)));

typedef const __attribute__((address_space(1))) void* gas_ptr;
typedef __attribute__((address_space(3))) void* las_ptr;

DEV_INLINE unsigned short f2bf(float f) {
    union { float f; unsigned u; } v; v.f = f;
    unsigned r = v.u + 0x7fffu + ((v.u >> 16) & 1u);   // RNE
    return (unsigned short)(r >> 16);
}
DEV_INLINE float bf2f(unsigned short u) {
    union { unsigned u; float f; } v; v.u = ((unsigned)u) << 16;
    return v.f;
}

// ---------------- casts ----------------

__global__ void cast_bf16_kernel(const float* __restrict__ src,
                                 unsigned short* __restrict__ dst, long n4) {
    long i = (long)blockIdx.x * blockDim.x + threadIdx.x;
    if (i >= n4) return;
    float4 a = ((const float4*)src)[i];
    ushort4 o;
    o.x = f2bf(a.x); o.y = f2bf(a.y); o.z = f2bf(a.z); o.w = f2bf(a.w);
    ((ushort4*)dst)[i] = o;
}

// src: R x C fp32 row-major (R,C multiples of 64). dst: C x R bf16 row-major (ld_dst).
__global__ void transpose_cast_kernel(const float* __restrict__ src, int C,
                                      unsigned short* __restrict__ dst, int ld_dst) {
    __shared__ float t[64][65];
    int c0 = blockIdx.x * 64, r0 = blockIdx.y * 64;
    int tx = threadIdx.x, ty = threadIdx.y;   // 64 x 16
    #pragma unroll
    for (int i = 0; i < 64; i += 16)
        t[ty + i][tx] = src[(long)(r0 + ty + i) * C + c0 + tx];
    __syncthreads();
    #pragma unroll
    for (int i = 0; i < 64; i += 16)
        dst[(long)(c0 + ty + i) * ld_dst + r0 + tx] = f2bf(t[tx][ty + i]);
}

__global__ void concat_bias_kernel(const float* __restrict__ bq,
                                   const float* __restrict__ bkv,
                                   float* __restrict__ out) {
    int i = blockIdx.x * 256 + threadIdx.x;
    if (i < 2304) out[i] = (i < 768) ? bq[i] : bkv[i - 768];
}

// ---------------- bf16 MFMA GEMM: C = A @ B + bias ----------------
// A: M x K bf16 row-major (lda). BT: N x K bf16 row-major (ldb) == B transposed.
// Tile 128x128, BK=64, 4 waves (each computes a 64x64 quadrant as 4x4 of 16x16x32 MFMAs).
// All dims assumed multiples of the tile (true for every call here).

template <bool OUT_BF16>
__global__ __launch_bounds__(256)
void gemm_bf16_kernel(const unsigned short* __restrict__ A, int lda,
                      const unsigned short* __restrict__ BT, int ldb,
                      const float* __restrict__ bias,
                      void* __restrict__ Cout, int ldc, int K) {
    __shared__ unsigned short As[128 * 64];
    __shared__ unsigned short Bs[128 * 64];
    const int tid = threadIdx.x;
    const int w = tid >> 6, lane = tid & 63;
    const int lm = lane & 15, quad = lane >> 4;
    const long tm = (long)blockIdx.y * 128;
    const long tn = (long)blockIdx.x * 128;
    const int m_off = (w & 1) * 64, n_off = (w >> 1) * 64;
    const int lrow8 = lane >> 3;        // 0..7: row within the 8-row chunk
    const int lcol = (lane & 7) * 8;    // k-offset (elements) within BK

    f32x4 acc[4][4] = {};

    for (int k0 = 0; k0 < K; k0 += 64) {
        __syncthreads();   // previous stage's LDS reads done before overwrite
        #pragma unroll
        for (int i = 0; i < 4; ++i) {
            const unsigned short* ga = A + (tm + w * 32 + i * 8 + lrow8) * lda + k0 + lcol;
            __builtin_amdgcn_global_load_lds((gas_ptr)ga,
                (las_ptr)(As + (w * 32 + i * 8) * 64), 16, 0, 0);
            const unsigned short* gb = BT + (tn + w * 32 + i * 8 + lrow8) * ldb + k0 + lcol;
            __builtin_amdgcn_global_load_lds((gas_ptr)gb,
                (las_ptr)(Bs + (w * 32 + i * 8) * 64), 16, 0, 0);
        }
        __syncthreads();   // compiler emits vmcnt(0) drain before barrier
        #pragma unroll
        for (int kk = 0; kk < 2; ++kk) {
            bf16x8 af[4], bfr[4];
            #pragma unroll
            for (int mi = 0; mi < 4; ++mi)
                af[mi] = *(const bf16x8*)(As + (m_off + mi * 16 + lm) * 64 + kk * 32 + quad * 8);
            #pragma unroll
            for (int ni = 0; ni < 4; ++ni)
                bfr[ni] = *(const bf16x8*)(Bs + (n_off + ni * 16 + lm) * 64 + kk * 32 + quad * 8);
            #pragma unroll
            for (int mi = 0; mi < 4; ++mi)
                #pragma unroll
                for (int ni = 0; ni < 4; ++ni)
                    acc[mi][ni] = __builtin_amdgcn_mfma_f32_16x16x32_bf16(
                        af[mi], bfr[ni], acc[mi][ni], 0, 0, 0);
        }
    }

    #pragma unroll
    for (int mi = 0; mi < 4; ++mi) {
        #pragma unroll
        for (int ni = 0; ni < 4; ++ni) {
            long col = tn + n_off + ni * 16 + lm;
            float bv = bias[col];
            #pragma unroll
            for (int r = 0; r < 4; ++r) {
                long row = tm + m_off + mi * 16 + quad * 4 + r;   // C/D: col=lane&15, row=quad*4+reg
                float v = acc[mi][ni][r] + bv;
                if (OUT_BF16)
                    ((unsigned short*)Cout)[row * ldc + col] = f2bf(v);
                else
                    ((float*)Cout)[row * ldc + col] = v;
            }
        }
    }
}

// ---------------- fused asymmetric attention ----------------
// qkv: (B*N) x 2304 fp32  [q | k_x | v_x] per row.
// kvs: (B*N*M) x 1536 bf16 [k_s | v_s] per row.
// attn_out: (B*N) x 768 bf16.
// One block per (b,h,n), 320 threads (5 waves). Scores: t<256 -> sg[t], t>=256 -> sl[t-256].
__global__ __launch_bounds__(320)
void attn_kernel(const float* __restrict__ qkv,
                 const unsigned short* __restrict__ kvs,
                 unsigned short* __restrict__ attn_out) {
    const int n = blockIdx.x, h = blockIdx.y, b = blockIdx.z;
    const int t = threadIdx.x;
    const int lane = t & 63, wid = t >> 6;
    __shared__ float q[64];
    __shared__ float wgt[320];
    __shared__ float red[8];
    __shared__ float part[5][64];

    const long row_bn = (long)(b * 256 + n);
    if (t < 64) q[t] = qkv[row_bn * 2304 + h * 64 + t];
    __syncthreads();

    float s;
    if (t < 256) {
        const float* krow = qkv + (long)(b * 256 + t) * 2304 + 768 + h * 64;
        float acc = 0.f;
        #pragma unroll
        for (int d = 0; d < 64; d += 4) {
            float4 k4 = *(const float4*)(krow + d);
            acc += q[d] * k4.x + q[d + 1] * k4.y + q[d + 2] * k4.z + q[d + 3] * k4.w;
        }
        s = acc;
    } else {
        const int m = t - 256;
        const unsigned short* ksrow = kvs + (row_bn * 64 + m) * 1536 + h * 64;
        float acc = 0.f;
        #pragma unroll
        for (int d = 0; d < 64; d += 2) {
            unsigned u = *(const unsigned*)(ksrow + d);
            acc += q[d] * bf2f((unsigned short)(u & 0xffffu))
                 + q[d + 1] * bf2f((unsigned short)(u >> 16));
        }
        s = acc;
    }
    s *= 0.125f;   // HD^-0.5

    // block max over 320
    float v = s;
    #pragma unroll
    for (int off = 32; off > 0; off >>= 1) v = fmaxf(v, __shfl_xor(v, off));
    if (lane == 0) red[wid] = v;
    __syncthreads();
    float mx = fmaxf(fmaxf(fmaxf(red[0], red[1]), fmaxf(red[2], red[3])), red[4]);
    float e = __expf(s - mx);

    // block sum over 320
    float v2 = e;
    #pragma unroll
    for (int off = 32; off > 0; off >>= 1) v2 += __shfl_xor(v2, off);
    __syncthreads();   // everyone done reading red before overwrite
    if (lane == 0) red[wid] = v2;
    __syncthreads();
    float denom = red[0] + red[1] + red[2] + red[3] + red[4];
    wgt[t] = e * (1.f / denom);
    __syncthreads();

    // output: waves 0..3 sum 64 global keys each (coalesced v_x row reads);
    // wave 4 sums the 64 sim values.
    const int d = lane, g = wid;
    float acc = 0.f;
    if (g < 4) {
        const float* vbase = qkv + 1536 + h * 64 + d;
        const int kk0 = b * 256 + g * 64;
        for (int kk = 0; kk < 64; ++kk)
            acc += wgt[g * 64 + kk] * vbase[(long)(kk0 + kk) * 2304];
    } else {
        const unsigned short* vsbase = kvs + row_bn * 64 * 1536 + 768 + h * 64 + d;
        for (int m = 0; m < 64; ++m)
            acc += wgt[256 + m] * bf2f(vsbase[(long)m * 1536]);
    }
    part[g][d] = acc;
    __syncthreads();
    if (t < 64) {
        float o = part[0][t] + part[1][t] + part[2][t] + part[3][t] + part[4][t];
        attn_out[row_bn * 768 + h * 64 + t] = f2bf(o);
    }
}

// ---------------- launch ----------------

extern "C" void kernel_launch(void* const* d_in, const int* in_sizes, int n_in,
                              void* d_out, int out_size, void* d_ws, size_t ws_size,
                              hipStream_t stream) {
    const float* x   = (const float*)d_in[0];   // (2,256,768)
    const float* sim = (const float*)d_in[1];   // (2,256,64,768)
    const float* Wq  = (const float*)d_in[2];   // (768,768)
    const float* bq  = (const float*)d_in[3];   // (768)
    const float* Wkv = (const float*)d_in[4];   // (768,1536)
    const float* bkv = (const float*)d_in[5];   // (1536)
    const float* Wp  = (const float*)d_in[6];   // (768,768)
    const float* bp  = (const float*)d_in[7];   // (768)
    float* out = (float*)d_out;                 // (2,256,768) fp32

    char* ws = (char*)d_ws;
    size_t off = 0;
    auto alloc = [&](size_t bytes) {
        char* p = ws + off;
        off += (bytes + 255) & ~(size_t)255;
        return p;
    };
    unsigned short* simb  = (unsigned short*)alloc(32768UL * 768 * 2);   // sim bf16
    unsigned short* kvs   = (unsigned short*)alloc(32768UL * 1536 * 2);  // kv_s bf16
    unsigned short* xb    = (unsigned short*)alloc(512UL * 768 * 2);     // x bf16
    unsigned short* w1t   = (unsigned short*)alloc(2304UL * 768 * 2);    // [Wq|Wkv]^T bf16
    unsigned short* wpt   = (unsigned short*)alloc(768UL * 768 * 2);     // Wp^T bf16
    float*          qkv   = (float*)alloc(512UL * 2304 * 4);             // q|k_x|v_x fp32
    unsigned short* attnb = (unsigned short*)alloc(512UL * 768 * 2);     // attn out bf16
    float*          bias1 = (float*)alloc(2304UL * 4);                   // [bq|bkv]

    // casts / transposes
    cast_bf16_kernel<<<(512L * 768 / 4 + 255) / 256, 256, 0, stream>>>(x, xb, 512L * 768 / 4);
    cast_bf16_kernel<<<(32768L * 768 / 4 + 255) / 256, 256, 0, stream>>>(sim, simb, 32768L * 768 / 4);
    transpose_cast_kernel<<<dim3(12, 12), dim3(64, 16), 0, stream>>>(Wq, 768, w1t, 768);
    transpose_cast_kernel<<<dim3(24, 12), dim3(64, 16), 0, stream>>>(Wkv, 1536, w1t + 768L * 768, 768);
    transpose_cast_kernel<<<dim3(12, 12), dim3(64, 16), 0, stream>>>(Wp, 768, wpt, 768);
    concat_bias_kernel<<<9, 256, 0, stream>>>(bq, bkv, bias1);

    // GEMM1: qkv = x @ [Wq|Wkv] + [bq|bkv]   (512 x 2304, K=768) -> fp32
    gemm_bf16_kernel<false><<<dim3(18, 4), 256, 0, stream>>>(
        xb, 768, w1t, 768, bias1, qkv, 2304, 768);

    // GEMM2: kv_s = sim @ Wkv + bkv   (32768 x 1536, K=768) -> bf16
    gemm_bf16_kernel<true><<<dim3(12, 256), 256, 0, stream>>>(
        simb, 768, w1t + 768L * 768, 768, bkv, kvs, 1536, 768);

    // fused attention
    attn_kernel<<<dim3(256, 12, 2), 320, 0, stream>>>(qkv, kvs, attnb);

    // GEMM3: out = attn @ Wp + bp   (512 x 768, K=768) -> fp32
    gemm_bf16_kernel<false><<<dim3(6, 4), 256, 0, stream>>>(
        attnb, 768, wpt, 768, bp, out, 768, 768);
}

// Round 2
// 387.332 us; speedup vs baseline: 1.1041x; 1.1041x over previous
//
#include <hip/hip_runtime.h>
#include <stdint.h>

#define DEV_INLINE __device__ __forceinline__

typedef __bf16 bf16x8 __attribute__((ext_vector_type(8)));
typedef float f32x4 __attribute__((ext_vector_type(4)));

typedef const __attribute__((address_space(1))) void* gas_ptr;
typedef __attribute__((address_space(3))) void* las_ptr;

DEV_INLINE unsigned short f2bf(float f) {
    union { float f; unsigned u; } v; v.f = f;
    unsigned r = v.u + 0x7fffu + ((v.u >> 16) & 1u);   // RNE
    return (unsigned short)(r >> 16);
}
DEV_INLINE float bf2f(unsigned short u) {
    union { unsigned u; float f; } v; v.u = ((unsigned)u) << 16;
    return v.f;
}

// ---------------- casts ----------------

__global__ void cast_bf16_kernel(const float* __restrict__ src,
                                 unsigned short* __restrict__ dst, long n4) {
    long i = (long)blockIdx.x * blockDim.x + threadIdx.x;
    if (i >= n4) return;
    float4 a = ((const float4*)src)[i];
    ushort4 o;
    o.x = f2bf(a.x); o.y = f2bf(a.y); o.z = f2bf(a.z); o.w = f2bf(a.w);
    ((ushort4*)dst)[i] = o;
}

// src: R x C fp32 row-major (R,C multiples of 64). dst: C x R bf16 row-major (ld_dst).
__global__ void transpose_cast_kernel(const float* __restrict__ src, int C,
                                      unsigned short* __restrict__ dst, int ld_dst) {
    __shared__ float t[64][65];
    int c0 = blockIdx.x * 64, r0 = blockIdx.y * 64;
    int tx = threadIdx.x, ty = threadIdx.y;   // 64 x 16
    #pragma unroll
    for (int i = 0; i < 64; i += 16)
        t[ty + i][tx] = src[(long)(r0 + ty + i) * C + c0 + tx];
    __syncthreads();
    #pragma unroll
    for (int i = 0; i < 64; i += 16)
        dst[(long)(c0 + ty + i) * ld_dst + r0 + tx] = f2bf(t[tx][ty + i]);
}

__global__ void concat_bias_kernel(const float* __restrict__ bq,
                                   const float* __restrict__ bkv,
                                   float* __restrict__ out) {
    int i = blockIdx.x * 256 + threadIdx.x;
    if (i < 2304) out[i] = (i < 768) ? bq[i] : bkv[i - 768];
}

// ---------------- bf16 MFMA GEMM: C = A @ B + bias ----------------
// A: M x K bf16 row-major (lda). BT: N x K bf16 row-major (ldb) == B transposed.
// Block tile (MI*32) x (NI*32), BK=64, 4 waves in 2x2; each wave owns a
// (MI*16)x(NI*16) quadrant of MIxNI 16x16x32 MFMAs.
// LDS chunk-XOR swizzle: LDS position p of row r holds global k-chunk p^(r&7)
// (chunk = 8 bf16 = 16 B). Staging write order (wave-uniform base + lane*16)
// is unchanged; we permute the global source column instead.

template <int MI, int NI, bool OUT_BF16, bool XCD_SWZ>
__global__ __launch_bounds__(256)
void gemm_bf16_kernel(const unsigned short* __restrict__ A, int lda,
                      const unsigned short* __restrict__ BT, int ldb,
                      const float* __restrict__ bias,
                      void* __restrict__ Cout, int ldc, int K,
                      int nx, int ypx) {
    constexpr int TR = MI * 32;   // tile rows (M)
    constexpr int TC = NI * 32;   // tile cols (N)
    __shared__ unsigned short As[TR * 64];
    __shared__ unsigned short Bs[TC * 64];
    const int tid = threadIdx.x;
    const int w = tid >> 6, lane = tid & 63;
    const int lm = lane & 15, quad = lane >> 4;
    int tx, ty;
    if (XCD_SWZ) {
        // consecutive HW block ids round-robin across 8 XCDs; give each XCD a
        // contiguous band of ypx y-tiles so each A-tile is fetched by one XCD.
        int L = blockIdx.x;
        int xcd = L & 7, slot = L >> 3;
        tx = slot % nx;
        ty = slot / nx + xcd * ypx;
    } else {
        tx = blockIdx.x; ty = blockIdx.y;
    }
    const long tm = (long)ty * TR;
    const long tn = (long)tx * TC;
    const int m_off = (w & 1) * MI * 16, n_off = (w >> 1) * NI * 16;
    const int lrow8 = lane >> 3;                        // 0..7 row within 8-row chunk
    const int lcol_sw = (((lane & 7) ^ lrow8) * 8);     // swizzled global k-chunk

    f32x4 acc[MI][NI];
    #pragma unroll
    for (int mi = 0; mi < MI; ++mi)
        #pragma unroll
        for (int ni = 0; ni < NI; ++ni) acc[mi][ni] = f32x4{0.f, 0.f, 0.f, 0.f};

    for (int k0 = 0; k0 < K; k0 += 64) {
        __syncthreads();   // previous stage's LDS reads done before overwrite
        #pragma unroll
        for (int i = 0; i < TR / 32; ++i) {
            int r0 = w * (TR / 4) + i * 8;
            const unsigned short* ga = A + (tm + r0 + lrow8) * lda + k0 + lcol_sw;
            __builtin_amdgcn_global_load_lds((gas_ptr)ga, (las_ptr)(As + r0 * 64), 16, 0, 0);
        }
        #pragma unroll
        for (int i = 0; i < TC / 32; ++i) {
            int r0 = w * (TC / 4) + i * 8;
            const unsigned short* gb = BT + (tn + r0 + lrow8) * ldb + k0 + lcol_sw;
            __builtin_amdgcn_global_load_lds((gas_ptr)gb, (las_ptr)(Bs + r0 * 64), 16, 0, 0);
        }
        __syncthreads();
        #pragma unroll
        for (int kk = 0; kk < 2; ++kk) {
            bf16x8 af[MI], bfr[NI];
            #pragma unroll
            for (int mi = 0; mi < MI; ++mi) {
                int r = m_off + mi * 16 + lm;
                af[mi] = *(const bf16x8*)(As + r * 64 + (((kk * 4 + quad) ^ (r & 7)) * 8));
            }
            #pragma unroll
            for (int ni = 0; ni < NI; ++ni) {
                int r = n_off + ni * 16 + lm;
                bfr[ni] = *(const bf16x8*)(Bs + r * 64 + (((kk * 4 + quad) ^ (r & 7)) * 8));
            }
            #pragma unroll
            for (int mi = 0; mi < MI; ++mi)
                #pragma unroll
                for (int ni = 0; ni < NI; ++ni)
                    acc[mi][ni] = __builtin_amdgcn_mfma_f32_16x16x32_bf16(
                        af[mi], bfr[ni], acc[mi][ni], 0, 0, 0);
        }
    }

    #pragma unroll
    for (int mi = 0; mi < MI; ++mi) {
        #pragma unroll
        for (int ni = 0; ni < NI; ++ni) {
            long col = tn + n_off + ni * 16 + lm;
            float bv = bias[col];
            #pragma unroll
            for (int r = 0; r < 4; ++r) {
                long row = tm + m_off + mi * 16 + quad * 4 + r;   // C/D: col=lane&15, row=quad*4+reg
                float v = acc[mi][ni][r] + bv;
                if (OUT_BF16)
                    ((unsigned short*)Cout)[row * ldc + col] = f2bf(v);
                else
                    ((float*)Cout)[row * ldc + col] = v;
            }
        }
    }
}

// ---------------- fused asymmetric attention ----------------
// qkv: (B*N) x 2304 fp32  [q | k_x | v_x] per row.
// kvs: (B*N*M) x 1536 bf16 [k_s | v_s] per row.
// attn_out: (B*N) x 768 bf16.
// One block per (b,h,n), 320 threads (5 waves). Scores: t<256 -> sg[t], t>=256 -> sl[t-256].
__global__ __launch_bounds__(320)
void attn_kernel(const float* __restrict__ qkv,
                 const unsigned short* __restrict__ kvs,
                 unsigned short* __restrict__ attn_out) {
    const int n = blockIdx.x, h = blockIdx.y, b = blockIdx.z;
    const int t = threadIdx.x;
    const int lane = t & 63, wid = t >> 6;
    __shared__ float q[64];
    __shared__ float wgt[320];
    __shared__ float red[8];
    __shared__ float part[5][64];

    const long row_bn = (long)(b * 256 + n);
    if (t < 64) q[t] = qkv[row_bn * 2304 + h * 64 + t];
    __syncthreads();

    float s;
    if (t < 256) {
        const float* krow = qkv + (long)(b * 256 + t) * 2304 + 768 + h * 64;
        float acc = 0.f;
        #pragma unroll
        for (int d = 0; d < 64; d += 4) {
            float4 k4 = *(const float4*)(krow + d);
            acc += q[d] * k4.x + q[d + 1] * k4.y + q[d + 2] * k4.z + q[d + 3] * k4.w;
        }
        s = acc;
    } else {
        const int m = t - 256;
        const unsigned short* ksrow = kvs + (row_bn * 64 + m) * 1536 + h * 64;
        float acc = 0.f;
        #pragma unroll
        for (int d = 0; d < 64; d += 2) {
            unsigned u = *(const unsigned*)(ksrow + d);
            acc += q[d] * bf2f((unsigned short)(u & 0xffffu))
                 + q[d + 1] * bf2f((unsigned short)(u >> 16));
        }
        s = acc;
    }
    s *= 0.125f;   // HD^-0.5

    // block max over 320
    float v = s;
    #pragma unroll
    for (int off = 32; off > 0; off >>= 1) v = fmaxf(v, __shfl_xor(v, off));
    if (lane == 0) red[wid] = v;
    __syncthreads();
    float mx = fmaxf(fmaxf(fmaxf(red[0], red[1]), fmaxf(red[2], red[3])), red[4]);
    float e = __expf(s - mx);

    // block sum over 320
    float v2 = e;
    #pragma unroll
    for (int off = 32; off > 0; off >>= 1) v2 += __shfl_xor(v2, off);
    __syncthreads();   // everyone done reading red before overwrite
    if (lane == 0) red[wid] = v2;
    __syncthreads();
    float denom = red[0] + red[1] + red[2] + red[3] + red[4];
    wgt[t] = e * (1.f / denom);
    __syncthreads();

    // output: waves 0..3 sum 64 global keys each (coalesced v_x row reads);
    // wave 4 sums the 64 sim values.
    const int d = lane, g = wid;
    float acc = 0.f;
    if (g < 4) {
        const float* vbase = qkv + 1536 + h * 64 + d;
        const int kk0 = b * 256 + g * 64;
        for (int kk = 0; kk < 64; ++kk)
            acc += wgt[g * 64 + kk] * vbase[(long)(kk0 + kk) * 2304];
    } else {
        const unsigned short* vsbase = kvs + row_bn * 64 * 1536 + 768 + h * 64 + d;
        for (int m = 0; m < 64; ++m)
            acc += wgt[256 + m] * bf2f(vsbase[(long)m * 1536]);
    }
    part[g][d] = acc;
    __syncthreads();
    if (t < 64) {
        float o = part[0][t] + part[1][t] + part[2][t] + part[3][t] + part[4][t];
        attn_out[row_bn * 768 + h * 64 + t] = f2bf(o);
    }
}

// ---------------- launch ----------------

extern "C" void kernel_launch(void* const* d_in, const int* in_sizes, int n_in,
                              void* d_out, int out_size, void* d_ws, size_t ws_size,
                              hipStream_t stream) {
    const float* x   = (const float*)d_in[0];   // (2,256,768)
    const float* sim = (const float*)d_in[1];   // (2,256,64,768)
    const float* Wq  = (const float*)d_in[2];   // (768,768)
    const float* bq  = (const float*)d_in[3];   // (768)
    const float* Wkv = (const float*)d_in[4];   // (768,1536)
    const float* bkv = (const float*)d_in[5];   // (1536)
    const float* Wp  = (const float*)d_in[6];   // (768,768)
    const float* bp  = (const float*)d_in[7];   // (768)
    float* out = (float*)d_out;                 // (2,256,768) fp32

    char* ws = (char*)d_ws;
    size_t off = 0;
    auto alloc = [&](size_t bytes) {
        char* p = ws + off;
        off += (bytes + 255) & ~(size_t)255;
        return p;
    };
    unsigned short* simb  = (unsigned short*)alloc(32768UL * 768 * 2);   // sim bf16
    unsigned short* kvs   = (unsigned short*)alloc(32768UL * 1536 * 2);  // kv_s bf16
    unsigned short* xb    = (unsigned short*)alloc(512UL * 768 * 2);     // x bf16
    unsigned short* w1t   = (unsigned short*)alloc(2304UL * 768 * 2);    // [Wq|Wkv]^T bf16
    unsigned short* wpt   = (unsigned short*)alloc(768UL * 768 * 2);     // Wp^T bf16
    float*          qkv   = (float*)alloc(512UL * 2304 * 4);             // q|k_x|v_x fp32
    unsigned short* attnb = (unsigned short*)alloc(512UL * 768 * 2);     // attn out bf16
    float*          bias1 = (float*)alloc(2304UL * 4);                   // [bq|bkv]

    // casts / transposes
    cast_bf16_kernel<<<(512L * 768 / 4 + 255) / 256, 256, 0, stream>>>(x, xb, 512L * 768 / 4);
    cast_bf16_kernel<<<(32768L * 768 / 4 + 255) / 256, 256, 0, stream>>>(sim, simb, 32768L * 768 / 4);
    transpose_cast_kernel<<<dim3(12, 12), dim3(64, 16), 0, stream>>>(Wq, 768, w1t, 768);
    transpose_cast_kernel<<<dim3(24, 12), dim3(64, 16), 0, stream>>>(Wkv, 1536, w1t + 768L * 768, 768);
    transpose_cast_kernel<<<dim3(12, 12), dim3(64, 16), 0, stream>>>(Wp, 768, wpt, 768);
    concat_bias_kernel<<<9, 256, 0, stream>>>(bq, bkv, bias1);

    // GEMM1: qkv = x @ [Wq|Wkv] + [bq|bkv]   (512 x 2304, K=768) -> fp32, 64x64 tiles
    gemm_bf16_kernel<2, 2, false, false><<<dim3(36, 8), 256, 0, stream>>>(
        xb, 768, w1t, 768, bias1, qkv, 2304, 768, 0, 0);

    // GEMM2: kv_s = sim @ Wkv + bkv   (32768 x 1536, K=768) -> bf16, 128x128 tiles,
    // XCD-swizzled 1-D grid: 3072 blocks = 8 XCDs x (12 x-tiles x 32 y-tiles)
    gemm_bf16_kernel<4, 4, true, true><<<3072, 256, 0, stream>>>(
        simb, 768, w1t + 768L * 768, 768, bkv, kvs, 1536, 768, 12, 32);

    // fused attention
    attn_kernel<<<dim3(256, 12, 2), 320, 0, stream>>>(qkv, kvs, attnb);

    // GEMM3: out = attn @ Wp + bp   (512 x 768, K=768) -> fp32, 64x64 tiles
    gemm_bf16_kernel<2, 2, false, false><<<dim3(12, 8), 256, 0, stream>>>(
        attnb, 768, wpt, 768, bp, out, 768, 768, 0, 0);
}